// Round 1
// baseline (1845.366 us; speedup 1.0000x reference)
//
#include <hip/hip_runtime.h>

#define D_ 1024
#define B_ 2
#define T_ 2048
#define F_ 2048
#define CHUNK 512
#define NCHUNK 4
#define EPS_ 1e-6f
#define RSCALE 0.044194173824159216f   // sqrt(2/1024)

// ---------------------------------------------------------------------------
// Generic fp32 SGEMM: C[M,N] = A[M,K] @ B[K,N], row-major, K % 16 == 0,
// M % 128 == 0, N % 128 == 0. EPI=0: plain store (row stride ldc).
// EPI=1: RFF epilogue: C[r, n] = RSCALE*cos(acc), C[r, n+D_] = RSCALE*sin(acc),
//        with row stride ldc (= 2048 for phi buffers).
// Tile 128x128, BK=16, 256 threads, 8x8 per thread (4+4 split).
// ---------------------------------------------------------------------------
template<int EPI>
__global__ __launch_bounds__(256)
void sgemm128(const float* __restrict__ A, const float* __restrict__ B,
              float* __restrict__ C, int M, int N, int K, int ldc) {
    __shared__ float As[16][132];
    __shared__ float Bs[16][132];
    const int tid = threadIdx.x;
    const int bm = blockIdx.x * 128;
    const int bn = blockIdx.y * 128;
    const int tx = tid & 15, ty = tid >> 4;
    float acc[2][2][4][4] = {};
    const float* Ab = A + (size_t)bm * K;
    const float* Bb = B + bn;

    for (int k0 = 0; k0 < K; k0 += 16) {
#pragma unroll
        for (int l = 0; l < 2; ++l) {
            int idx = tid + l * 256;            // 0..511
            int r  = idx >> 2;                  // 0..127
            int c4 = (idx & 3) << 2;            // 0,4,8,12
            float4 a = *(const float4*)(Ab + (size_t)r * K + k0 + c4);
            As[c4 + 0][r] = a.x; As[c4 + 1][r] = a.y;
            As[c4 + 2][r] = a.z; As[c4 + 3][r] = a.w;
            int rb = idx >> 5;                  // 0..15
            int cb = (idx & 31) << 2;           // 0..124
            *(float4*)(&Bs[rb][cb]) = *(const float4*)(Bb + (size_t)(k0 + rb) * N + cb);
        }
        __syncthreads();
#pragma unroll
        for (int k = 0; k < 16; ++k) {
            float4 a0 = *(float4*)(&As[k][ty * 4]);
            float4 a1 = *(float4*)(&As[k][64 + ty * 4]);
            float4 b0 = *(float4*)(&Bs[k][tx * 4]);
            float4 b1 = *(float4*)(&Bs[k][64 + tx * 4]);
            float av[2][4] = {{a0.x, a0.y, a0.z, a0.w}, {a1.x, a1.y, a1.z, a1.w}};
            float bv[2][4] = {{b0.x, b0.y, b0.z, b0.w}, {b1.x, b1.y, b1.z, b1.w}};
#pragma unroll
            for (int ri = 0; ri < 2; ++ri)
#pragma unroll
                for (int i = 0; i < 4; ++i)
#pragma unroll
                    for (int ci = 0; ci < 2; ++ci)
#pragma unroll
                        for (int j = 0; j < 4; ++j)
                            acc[ri][ci][i][j] = fmaf(av[ri][i], bv[ci][j], acc[ri][ci][i][j]);
        }
        __syncthreads();
    }

#pragma unroll
    for (int ri = 0; ri < 2; ++ri)
#pragma unroll
        for (int i = 0; i < 4; ++i) {
            int R = bm + ri * 64 + ty * 4 + i;
#pragma unroll
            for (int ci = 0; ci < 2; ++ci) {
                int col = bn + ci * 64 + tx * 4;
                if (EPI == 0) {
                    float4 v = make_float4(acc[ri][ci][i][0], acc[ri][ci][i][1],
                                           acc[ri][ci][i][2], acc[ri][ci][i][3]);
                    *(float4*)(&C[(size_t)R * ldc + col]) = v;
                } else {
                    float cs[4], sn[4];
#pragma unroll
                    for (int j = 0; j < 4; ++j)
                        __sincosf(acc[ri][ci][i][j], &sn[j], &cs[j]);
                    float4 cv = make_float4(RSCALE * cs[0], RSCALE * cs[1],
                                            RSCALE * cs[2], RSCALE * cs[3]);
                    float4 sv = make_float4(RSCALE * sn[0], RSCALE * sn[1],
                                            RSCALE * sn[2], RSCALE * sn[3]);
                    *(float4*)(&C[(size_t)R * ldc + col])      = cv;
                    *(float4*)(&C[(size_t)R * ldc + col + D_]) = sv;
                }
            }
        }
}

// ---------------------------------------------------------------------------
// P[b][c][t][s] = (s<=t) ? dot(Qphi[b, c*C+t, :], Kphi[b, c*C+s, :]) : 0
// grid (256 = 16x16 tiles of 32x32, NCHUNK, B_), 256 threads, 2x2 per thread.
// ---------------------------------------------------------------------------
__global__ __launch_bounds__(256)
void pall_kernel(const float* __restrict__ Qp, const float* __restrict__ Kp,
                 float* __restrict__ P) {
    const int tt = blockIdx.x >> 4, ts = blockIdx.x & 15;
    const int c = blockIdx.y, b = blockIdx.z;
    const int t0 = tt * 32, s0 = ts * 32;
    float* Pc = P + (((size_t)b * NCHUNK + c) * CHUNK) * CHUNK;
    const int tid = threadIdx.x;
    if (tt < ts) {  // strictly upper tile: zero-fill
        int r = tid >> 3, c4 = (tid & 7) << 2;
        *(float4*)(&Pc[(size_t)(t0 + r) * CHUNK + s0 + c4]) = make_float4(0, 0, 0, 0);
        return;
    }
    __shared__ float Qs[32][36];
    __shared__ float Ks[32][36];
    const int tx = tid & 15, ty = tid >> 4;
    float acc[2][2] = {};
    const float* Qb = Qp + ((size_t)b * T_ + c * CHUNK + t0) * F_;
    const float* Kb = Kp + ((size_t)b * T_ + c * CHUNK + s0) * F_;
    for (int f0 = 0; f0 < F_; f0 += 32) {
        int r = tid >> 3, c4 = (tid & 7) << 2;
        *(float4*)(&Qs[r][c4]) = *(const float4*)(Qb + (size_t)r * F_ + f0 + c4);
        *(float4*)(&Ks[r][c4]) = *(const float4*)(Kb + (size_t)r * F_ + f0 + c4);
        __syncthreads();
#pragma unroll
        for (int k = 0; k < 32; ++k) {
            float q0 = Qs[ty * 2][k],     q1 = Qs[ty * 2 + 1][k];
            float k0v = Ks[tx * 2][k],    k1v = Ks[tx * 2 + 1][k];
            acc[0][0] = fmaf(q0, k0v, acc[0][0]);
            acc[0][1] = fmaf(q0, k1v, acc[0][1]);
            acc[1][0] = fmaf(q1, k0v, acc[1][0]);
            acc[1][1] = fmaf(q1, k1v, acc[1][1]);
        }
        __syncthreads();
    }
#pragma unroll
    for (int i = 0; i < 2; ++i)
#pragma unroll
        for (int j = 0; j < 2; ++j) {
            int t = t0 + ty * 2 + i, s = s0 + tx * 2 + j;
            Pc[(size_t)t * CHUNK + s] = (s <= t) ? acc[i][j] : 0.0f;
        }
}

// ---------------------------------------------------------------------------
// Per-chunk column sums of Kphi -> Zpre[b][c][f]; then exclusive prefix in place.
// ---------------------------------------------------------------------------
__global__ __launch_bounds__(256)
void csum_kernel(const float* __restrict__ Kp, float* __restrict__ Zpre) {
    const int f = blockIdx.x * 256 + threadIdx.x;
    const int c = blockIdx.y, b = blockIdx.z;
    const float* base = Kp + ((size_t)b * T_ + c * CHUNK) * F_ + f;
    float acc = 0.f;
    for (int s = 0; s < CHUNK; ++s) acc += base[(size_t)s * F_];
    Zpre[((size_t)b * NCHUNK + c) * F_ + f] = acc;
}

__global__ __launch_bounds__(256)
void zprefix_kernel(float* __restrict__ Zpre) {
    const int f = blockIdx.x * 256 + threadIdx.x;
    const int b = blockIdx.y;
    float run = 0.f;
    for (int c = 0; c < NCHUNK; ++c) {
        size_t idx = ((size_t)b * NCHUNK + c) * F_ + f;
        float v = Zpre[idx];
        Zpre[idx] = run;     // exclusive prefix
        run += v;
    }
}

// ---------------------------------------------------------------------------
// den[b][t] = dot(Qphi[b,t,:], Zpre[b, chunk(t), :]) + rowsum(P[b,chunk,t,:])
// grid (T_/4, B_), 4 waves/block, one t per wave.
// ---------------------------------------------------------------------------
__global__ __launch_bounds__(256)
void den_kernel(const float* __restrict__ Qp, const float* __restrict__ Zpre,
                const float* __restrict__ P, float* __restrict__ den) {
    const int b = blockIdx.y;
    const int w = threadIdx.x >> 6, lane = threadIdx.x & 63;
    const int t = blockIdx.x * 4 + w;
    const int c = t / CHUNK, tin = t % CHUNK;
    const float* q = Qp + ((size_t)b * T_ + t) * F_;
    const float* z = Zpre + ((size_t)b * NCHUNK + c) * F_;
    float acc = 0.f;
    for (int f = lane; f < F_; f += 64) acc = fmaf(q[f], z[f], acc);
    const float* prow = P + (((size_t)b * NCHUNK + c) * CHUNK + tin) * CHUNK;
    for (int s = lane; s < CHUNK; s += 64) acc += prow[s];
#pragma unroll
    for (int off = 32; off; off >>= 1) acc += __shfl_down(acc, off);
    if (lane == 0) den[(size_t)b * T_ + t] = acc;
}

// ---------------------------------------------------------------------------
// gamma_intra = P @ V (block-diagonal per chunk), written into G.
// grid (8*16, NCHUNK, B_): 64x64 tiles, K=CHUNK.
// ---------------------------------------------------------------------------
__global__ __launch_bounds__(256)
void intra_kernel(const float* __restrict__ P, const float* __restrict__ V,
                  float* __restrict__ G) {
    const int rt = blockIdx.x >> 4, ct = blockIdx.x & 15;
    const int c = blockIdx.y, b = blockIdx.z;
    const float* Pa = P + (((size_t)b * NCHUNK + c) * CHUNK + rt * 64) * CHUNK;
    const float* Vb = V + ((size_t)b * T_ + c * CHUNK) * D_ + ct * 64;
    float* Gb = G + ((size_t)b * T_ + c * CHUNK + rt * 64) * D_ + ct * 64;
    __shared__ float As[16][68];
    __shared__ float Bs[16][68];
    const int tid = threadIdx.x, tx = tid & 15, ty = tid >> 4;
    float acc[4][4] = {};
    for (int k0 = 0; k0 < CHUNK; k0 += 16) {
        int r = tid >> 2, c4 = (tid & 3) << 2;
        float4 a = *(const float4*)(Pa + (size_t)r * CHUNK + k0 + c4);
        As[c4 + 0][r] = a.x; As[c4 + 1][r] = a.y;
        As[c4 + 2][r] = a.z; As[c4 + 3][r] = a.w;
        int rb = tid >> 4, cb = (tid & 15) << 2;
        *(float4*)(&Bs[rb][cb]) = *(const float4*)(Vb + (size_t)(k0 + rb) * D_ + cb);
        __syncthreads();
#pragma unroll
        for (int k = 0; k < 16; ++k) {
            float4 av = *(float4*)(&As[k][ty * 4]);
            float4 bv = *(float4*)(&Bs[k][tx * 4]);
            float aa[4] = {av.x, av.y, av.z, av.w};
            float bb[4] = {bv.x, bv.y, bv.z, bv.w};
#pragma unroll
            for (int i = 0; i < 4; ++i)
#pragma unroll
                for (int j = 0; j < 4; ++j)
                    acc[i][j] = fmaf(aa[i], bb[j], acc[i][j]);
        }
        __syncthreads();
    }
#pragma unroll
    for (int i = 0; i < 4; ++i)
        *(float4*)(&Gb[(size_t)(ty * 4 + i) * D_ + tx * 4]) =
            make_float4(acc[i][0], acc[i][1], acc[i][2], acc[i][3]);
}

// ---------------------------------------------------------------------------
// gamma rows of chunk c: G = (Qphi_c @ S + G_intra) / (den + eps)
// grid (16*16, B_): 32x64 tiles, K=F_.
// ---------------------------------------------------------------------------
__global__ __launch_bounds__(256)
void gamma_kernel(const float* __restrict__ Qp, const float* __restrict__ S,
                  const float* __restrict__ den, float* __restrict__ G, int c) {
    const int rt = blockIdx.x >> 4, ct = blockIdx.x & 15;
    const int b = blockIdx.y;
    const int row0 = c * CHUNK + rt * 32;
    const float* Qb = Qp + ((size_t)b * T_ + row0) * F_;
    const float* Sb = S + (size_t)b * F_ * D_ + ct * 64;
    float* Gb = G + ((size_t)b * T_ + row0) * D_ + ct * 64;
    const float* db = den + (size_t)b * T_ + row0;
    __shared__ float As[32][36];   // transposed: As[k][r]
    __shared__ float Bs[32][68];
    const int tid = threadIdx.x, tx = tid & 15, ty = tid >> 4;
    float acc[2][4] = {};
    for (int k0 = 0; k0 < F_; k0 += 32) {
        int r = tid >> 3, c4 = (tid & 7) << 2;
        float4 a = *(const float4*)(Qb + (size_t)r * F_ + k0 + c4);
        As[c4 + 0][r] = a.x; As[c4 + 1][r] = a.y;
        As[c4 + 2][r] = a.z; As[c4 + 3][r] = a.w;
#pragma unroll
        for (int l = 0; l < 2; ++l) {
            int idx = tid + l * 256;
            int rb = idx >> 4, cb = (idx & 15) << 2;
            *(float4*)(&Bs[rb][cb]) = *(const float4*)(Sb + (size_t)(k0 + rb) * D_ + cb);
        }
        __syncthreads();
#pragma unroll
        for (int k = 0; k < 32; ++k) {
            float a0 = As[k][ty * 2], a1 = As[k][ty * 2 + 1];
            float4 bv = *(float4*)(&Bs[k][tx * 4]);
            acc[0][0] = fmaf(a0, bv.x, acc[0][0]);
            acc[0][1] = fmaf(a0, bv.y, acc[0][1]);
            acc[0][2] = fmaf(a0, bv.z, acc[0][2]);
            acc[0][3] = fmaf(a0, bv.w, acc[0][3]);
            acc[1][0] = fmaf(a1, bv.x, acc[1][0]);
            acc[1][1] = fmaf(a1, bv.y, acc[1][1]);
            acc[1][2] = fmaf(a1, bv.z, acc[1][2]);
            acc[1][3] = fmaf(a1, bv.w, acc[1][3]);
        }
        __syncthreads();
    }
#pragma unroll
    for (int i = 0; i < 2; ++i) {
        int r = ty * 2 + i;
        float dd = db[r] + EPS_;
        float4 g = *(float4*)(&Gb[(size_t)r * D_ + tx * 4]);
        g.x = (acc[i][0] + g.x) / dd;
        g.y = (acc[i][1] + g.y) / dd;
        g.z = (acc[i][2] + g.z) / dd;
        g.w = (acc[i][3] + g.w) / dd;
        *(float4*)(&Gb[(size_t)r * D_ + tx * 4]) = g;
    }
}

// ---------------------------------------------------------------------------
// S[b] += Kphi_c^T @ V_c   (F x D += (F x C)(C x D))
// grid (32*16, B_): 64x64 tiles, K=CHUNK.
// ---------------------------------------------------------------------------
__global__ __launch_bounds__(256)
void supd_kernel(const float* __restrict__ Kp, const float* __restrict__ V,
                 float* __restrict__ S, int c) {
    const int ft = blockIdx.x >> 4, dt = blockIdx.x & 15;
    const int b = blockIdx.y;
    const float* Kb = Kp + ((size_t)b * T_ + c * CHUNK) * F_ + ft * 64;
    const float* Vb = V + ((size_t)b * T_ + c * CHUNK) * D_ + dt * 64;
    float* Sb = S + (size_t)b * F_ * D_ + (size_t)ft * 64 * D_ + dt * 64;
    __shared__ float Ks[16][68];
    __shared__ float Vs[16][68];
    const int tid = threadIdx.x, tx = tid & 15, ty = tid >> 4;
    float acc[4][4] = {};
    for (int k0 = 0; k0 < CHUNK; k0 += 16) {
        int rb = tid >> 4, cb = (tid & 15) << 2;
        *(float4*)(&Ks[rb][cb]) = *(const float4*)(Kb + (size_t)(k0 + rb) * F_ + cb);
        *(float4*)(&Vs[rb][cb]) = *(const float4*)(Vb + (size_t)(k0 + rb) * D_ + cb);
        __syncthreads();
#pragma unroll
        for (int k = 0; k < 16; ++k) {
            float4 av = *(float4*)(&Ks[k][ty * 4]);   // f-fragment
            float4 bv = *(float4*)(&Vs[k][tx * 4]);   // d-fragment
            float aa[4] = {av.x, av.y, av.z, av.w};
            float bb[4] = {bv.x, bv.y, bv.z, bv.w};
#pragma unroll
            for (int i = 0; i < 4; ++i)
#pragma unroll
                for (int j = 0; j < 4; ++j)
                    acc[i][j] = fmaf(aa[i], bb[j], acc[i][j]);
        }
        __syncthreads();
    }
#pragma unroll
    for (int i = 0; i < 4; ++i) {
        float4* p = (float4*)(&Sb[(size_t)(ty * 4 + i) * D_ + tx * 4]);
        float4 s = *p;
        s.x += acc[i][0]; s.y += acc[i][1]; s.z += acc[i][2]; s.w += acc[i][3];
        *p = s;
    }
}

// ---------------------------------------------------------------------------
extern "C" void kernel_launch(void* const* d_in, const int* in_sizes, int n_in,
                              void* d_out, int out_size, void* d_ws, size_t ws_size,
                              hipStream_t stream) {
    const float* x     = (const float*)d_in[0];
    const float* Wq    = (const float*)d_in[1];
    const float* Wk    = (const float*)d_in[2];
    const float* Wv    = (const float*)d_in[3];
    const float* Wo    = (const float*)d_in[4];
    const float* omega = (const float*)d_in[5];
    float* out = (float*)d_out;
    float* ws = (float*)d_ws;

    // workspace layout (floats); total ~128.1 MB
    float* Wqo   = ws;                       // 1,048,576
    float* Wko   = Wqo + 1048576;            // 1,048,576
    float* V     = Wko + 1048576;            // 4,194,304
    float* Qphi  = V + 4194304;              // 8,388,608
    float* Kphi  = Qphi + 8388608;           // 8,388,608
    float* gamma = Kphi + 8388608;           // 4,194,304
    float* S     = gamma + 4194304;          // 4,194,304
    float* P     = S + 4194304;              // 2,097,152
    float* den   = P + 2097152;              // 4,096
    float* Zpre  = den + 4096;               // 32,768

    const int M = B_ * T_;  // 4096

    hipMemsetAsync(S, 0, (size_t)B_ * F_ * D_ * sizeof(float), stream);

    // Folded projection weights: Wqo = Wq@omega, Wko = Wk@omega
    sgemm128<0><<<dim3(8, 8), 256, 0, stream>>>(Wq, omega, Wqo, D_, D_, D_, D_);
    sgemm128<0><<<dim3(8, 8), 256, 0, stream>>>(Wk, omega, Wko, D_, D_, D_, D_);

    // V = x@Wv ; Qphi = rff(x@Wqo) ; Kphi = rff(x@Wko)
    sgemm128<0><<<dim3(M / 128, 8), 256, 0, stream>>>(x, Wv, V, M, D_, D_, D_);
    sgemm128<1><<<dim3(M / 128, 8), 256, 0, stream>>>(x, Wqo, Qphi, M, D_, D_, F_);
    sgemm128<1><<<dim3(M / 128, 8), 256, 0, stream>>>(x, Wko, Kphi, M, D_, D_, F_);

    // Z prefix per chunk
    csum_kernel<<<dim3(F_ / 256, NCHUNK, B_), 256, 0, stream>>>(Kphi, Zpre);
    zprefix_kernel<<<dim3(F_ / 256, B_), 256, 0, stream>>>(Zpre);

    // All-chunk masked P, den, and intra-chunk gamma contribution
    pall_kernel<<<dim3(256, NCHUNK, B_), 256, 0, stream>>>(Qphi, Kphi, P);
    den_kernel<<<dim3(T_ / 4, B_), 256, 0, stream>>>(Qphi, Zpre, P, den);
    intra_kernel<<<dim3(128, NCHUNK, B_), 256, 0, stream>>>(P, V, gamma);

    // Sequential chunk loop: inter-chunk gamma, then S update
    for (int c = 0; c < NCHUNK; ++c) {
        gamma_kernel<<<dim3(256, B_), 256, 0, stream>>>(Qphi, S, den, gamma, c);
        supd_kernel<<<dim3(512, B_), 256, 0, stream>>>(Kphi, V, S, c);
    }

    // out = gamma @ Wo
    sgemm128<0><<<dim3(M / 128, 8), 256, 0, stream>>>(gamma, Wo, out, M, D_, D_, D_);
}